// Round 6
// baseline (259.647 us; speedup 1.0000x reference)
//
#include <hip/hip_runtime.h>

// v6b: v0 structure (best measured) + NON-TEMPORAL output stores.
// (v6 failed to compile: __builtin_nontemporal_store rejects HIP_vector_type*;
//  use a native clang ext_vector_type for the store path.)
// Five structurally distinct kernels all pinned at ~87us = 3.1 TB/s through
// the vector-memory path regardless of MLP/occupancy/shape => in-flight-cap
// x latency regime. nt stores attack the remaining levers: (a) kill any
// read-for-ownership fetch of output lines, (b) stop store-allocations from
// thrashing the input set out of L3 (raising read latency).
#define PTS 256

typedef float floatx4 __attribute__((ext_vector_type(4)));

__global__ __launch_bounds__(256) void cov_proj_kernel(
    const float4* __restrict__ rot,     // (N,4) as float4
    const float*  __restrict__ mod,     // (1,)
    const float2* __restrict__ scale,   // (N,2) as float2
    const float*  __restrict__ p_k,     // (N,3)
    const float4* __restrict__ vm,      // (N,16) as 4x float4 per row
    float*        __restrict__ out,     // (N,9)
    int n)
{
    __shared__ __attribute__((aligned(16))) float lds_out[PTS * 9];  // 9 KiB

    const int t = threadIdx.x;
    const int base = blockIdx.x * PTS;
    const int i = base + t;

    if (i < n) {
        float4 q = rot[i];
        float r = q.x, x = q.y, y = q.z, z = q.w;
        float m = mod[0];
        float2 sc = scale[i];
        float s0 = m * sc.x;
        float s1 = m * sc.y;

        float R00 = 1.0f - 2.0f * (y * y + z * z);
        float R10 = 2.0f * (x * y + r * z);
        float R20 = 2.0f * (x * z - r * y);
        float R01 = 2.0f * (x * y - r * z);
        float R11 = 1.0f - 2.0f * (x * x + z * z);
        float R21 = 2.0f * (y * z + r * x);

        float u0 = s0 * R00, u1 = s0 * R10, u2 = s0 * R20;
        float v0 = s1 * R01, v1 = s1 * R11, v2 = s1 * R21;

        float p0 = p_k[3 * i + 0];
        float p1 = p_k[3 * i + 1];
        float p2 = p_k[3 * i + 2];

        float4 vm0 = vm[4 * i + 0];
        float4 vm1 = vm[4 * i + 1];
        float4 vm2 = vm[4 * i + 2];
        float4 vm3 = vm[4 * i + 3];

        float* o = &lds_out[9 * t];     // banks (9t+j)%32: <=2 lanes/bank -> free
        o[0] = vm0.x * u0 + vm1.x * u1 + vm2.x * u2;
        o[1] = vm0.x * v0 + vm1.x * v1 + vm2.x * v2;
        o[2] = vm0.x * p0 + vm1.x * p1 + vm2.x * p2 + vm3.x;
        o[3] = vm0.y * u0 + vm1.y * u1 + vm2.y * u2;
        o[4] = vm0.y * v0 + vm1.y * v1 + vm2.y * v2;
        o[5] = vm0.y * p0 + vm1.y * p1 + vm2.y * p2 + vm3.y;
        o[6] = vm0.z * u0 + vm1.z * u1 + vm2.z * u2;
        o[7] = vm0.z * v0 + vm1.z * v1 + vm2.z * v2;
        o[8] = vm0.z * p0 + vm1.z * p1 + vm2.z * p2 + vm3.z;
    }
    __syncthreads();

    const int points = min(PTS, n - base);
    const size_t out_base = (size_t)base * 9;

    if (points == PTS) {
        // Full block: 2304 floats = 576 float4, contiguous & 16B-aligned
        // (out_base*4 = blockIdx*9216 bytes, 9216 % 16 == 0).
        const floatx4* lo4 = (const floatx4*)lds_out;
        floatx4* go4 = (floatx4*)(out + out_base);
        #pragma unroll
        for (int k = t; k < (PTS * 9) / 4; k += 256) {
            // Streaming store (nt flag): no L2/L3 allocate, no RFO.
            __builtin_nontemporal_store(lo4[k], &go4[k]);
        }
    } else {
        const int total = points * 9;
        for (int k = t; k < total; k += 256) {
            __builtin_nontemporal_store(lds_out[k], &out[out_base + k]);
        }
    }
}

extern "C" void kernel_launch(void* const* d_in, const int* in_sizes, int n_in,
                              void* d_out, int out_size, void* d_ws, size_t ws_size,
                              hipStream_t stream) {
    const float4* rot   = (const float4*)d_in[0];
    const float*  mod   = (const float*)d_in[1];
    const float2* scale = (const float2*)d_in[2];
    const float*  p_k   = (const float*)d_in[3];
    const float4* vm    = (const float4*)d_in[4];
    float* out = (float*)d_out;

    int n = in_sizes[0] / 4;  // rot has N*4 elements
    int block = 256;
    int grid = (n + PTS - 1) / PTS;
    cov_proj_kernel<<<grid, block, 0, stream>>>(rot, mod, scale, p_k, vm, out, n);
}

// Round 7
// 257.772 us; speedup vs baseline: 1.0073x; 1.0073x over previous
//
#include <hip/hip_runtime.h>

// v7: v0 structure + ISA-level cache-policy output stores (sc0 sc1 nt).
// Diagnosis: 6 structurally distinct kernels pinned at ~88us = 3.1 TB/s
// combined => per-CU outstanding-line cap x avg latency. Only software lever
// left: cut avg READ latency by keeping the 200MB input L3-resident.
// FETCH_SIZE=97.7MB says half the input misses L3 each iter even though it
// fits in 256MB -> the 72MB output stream is evicting it. The HIP nt builtin
// (nt bit only, L1/L2 hint) didn't change FETCH; sc0+sc1 (system scope) is
// the ISA lever that skips intermediate-cache allocation on the store path.
#define PTS 256

typedef float floatx4 __attribute__((ext_vector_type(4)));

__global__ __launch_bounds__(256) void cov_proj_kernel(
    const float4* __restrict__ rot,     // (N,4) as float4
    const float*  __restrict__ mod,     // (1,)
    const float2* __restrict__ scale,   // (N,2) as float2
    const float*  __restrict__ p_k,     // (N,3)
    const float4* __restrict__ vm,      // (N,16) as 4x float4 per row
    float*        __restrict__ out,     // (N,9)
    int n)
{
    __shared__ __attribute__((aligned(16))) float lds_out[PTS * 9];  // 9 KiB

    const int t = threadIdx.x;
    const int base = blockIdx.x * PTS;
    const int i = base + t;

    if (i < n) {
        float4 q = rot[i];
        float r = q.x, x = q.y, y = q.z, z = q.w;
        float m = mod[0];
        float2 sc = scale[i];
        float s0 = m * sc.x;
        float s1 = m * sc.y;

        float R00 = 1.0f - 2.0f * (y * y + z * z);
        float R10 = 2.0f * (x * y + r * z);
        float R20 = 2.0f * (x * z - r * y);
        float R01 = 2.0f * (x * y - r * z);
        float R11 = 1.0f - 2.0f * (x * x + z * z);
        float R21 = 2.0f * (y * z + r * x);

        float u0 = s0 * R00, u1 = s0 * R10, u2 = s0 * R20;
        float v0 = s1 * R01, v1 = s1 * R11, v2 = s1 * R21;

        float p0 = p_k[3 * i + 0];
        float p1 = p_k[3 * i + 1];
        float p2 = p_k[3 * i + 2];

        float4 vm0 = vm[4 * i + 0];
        float4 vm1 = vm[4 * i + 1];
        float4 vm2 = vm[4 * i + 2];
        float4 vm3 = vm[4 * i + 3];

        float* o = &lds_out[9 * t];     // banks (9t+j)%32: <=2 lanes/bank -> free
        o[0] = vm0.x * u0 + vm1.x * u1 + vm2.x * u2;
        o[1] = vm0.x * v0 + vm1.x * v1 + vm2.x * v2;
        o[2] = vm0.x * p0 + vm1.x * p1 + vm2.x * p2 + vm3.x;
        o[3] = vm0.y * u0 + vm1.y * u1 + vm2.y * u2;
        o[4] = vm0.y * v0 + vm1.y * v1 + vm2.y * v2;
        o[5] = vm0.y * p0 + vm1.y * p1 + vm2.y * p2 + vm3.y;
        o[6] = vm0.z * u0 + vm1.z * u1 + vm2.z * u2;
        o[7] = vm0.z * v0 + vm1.z * v1 + vm2.z * v2;
        o[8] = vm0.z * p0 + vm1.z * p1 + vm2.z * p2 + vm3.z;
    }
    __syncthreads();

    const int points = min(PTS, n - base);
    const size_t out_base = (size_t)base * 9;

    if (points == PTS) {
        // Full block: 2304 floats = 576 float4, contiguous & 16B-aligned
        // (out_base*4 = blockIdx*9216 bytes, 9216 % 16 == 0).
        const floatx4* lo4 = (const floatx4*)lds_out;
        floatx4* go4 = (floatx4*)(out + out_base);
        #pragma unroll
        for (int k = t; k < (PTS * 9) / 4; k += 256) {
            floatx4 val = lo4[k];   // compiler inserts lgkmcnt wait before asm use
            // System-scope streaming store: sc0 sc1 = no intermediate-cache
            // allocation, nt = non-temporal. Protects L3 input residency.
            asm volatile("global_store_dwordx4 %0, %1, off sc0 sc1 nt"
                         :: "v"(&go4[k]), "v"(val) : "memory");
        }
    } else {
        const int total = points * 9;
        for (int k = t; k < total; k += 256) {
            __builtin_nontemporal_store(lds_out[k], &out[out_base + k]);
        }
    }
}

extern "C" void kernel_launch(void* const* d_in, const int* in_sizes, int n_in,
                              void* d_out, int out_size, void* d_ws, size_t ws_size,
                              hipStream_t stream) {
    const float4* rot   = (const float4*)d_in[0];
    const float*  mod   = (const float*)d_in[1];
    const float2* scale = (const float2*)d_in[2];
    const float*  p_k   = (const float*)d_in[3];
    const float4* vm    = (const float4*)d_in[4];
    float* out = (float*)d_out;

    int n = in_sizes[0] / 4;  // rot has N*4 elements
    int block = 256;
    int grid = (n + PTS - 1) / PTS;
    cov_proj_kernel<<<grid, block, 0, stream>>>(rot, mod, scale, p_k, vm, out, n);
}

// Round 8
// 255.313 us; speedup vs baseline: 1.0170x; 1.0096x over previous
//
#include <hip/hip_runtime.h>

// v8: BARRIER-FREE. v0's proven layout, but the LDS output transpose is
// per-WAVE (2304B private slice) instead of per-block: __syncthreads()
// replaced by an in-wave s_waitcnt lgkmcnt(0). Rationale: 7 structurally
// distinct kernels pinned at 3.13 TB/s = exactly half the m13 copy ubench
// (6.29 TB/s) on the same vector path; the one structural element all 7
// share and the copy lacks is the block-wide barrier coupling 4 waves'
// load tails + block-quantum drain. Waves now free-run like the copy.
#define PTS 256

__global__ __launch_bounds__(256) void cov_proj_kernel(
    const float4* __restrict__ rot,     // (N,4) as float4
    const float*  __restrict__ mod,     // (1,)
    const float2* __restrict__ scale,   // (N,2) as float2
    const float*  __restrict__ p_k,     // (N,3)
    const float4* __restrict__ vm,      // (N,16) as 4x float4 per row
    float*        __restrict__ out,     // (N,9)
    int n)
{
    __shared__ __attribute__((aligned(16))) float lds_out[PTS * 9];  // 9 KiB

    const int t = threadIdx.x;
    const int w = t >> 6;               // wave id 0..3
    const int l = t & 63;               // lane id
    const int base = blockIdx.x * PTS;
    const int i = base + t;

    float* wlds = &lds_out[w * 576];    // this wave's private 576-float slice

    if (i < n) {
        float4 q = rot[i];
        float r = q.x, x = q.y, y = q.z, z = q.w;
        float m = mod[0];
        float2 sc = scale[i];
        float s0 = m * sc.x;
        float s1 = m * sc.y;

        float R00 = 1.0f - 2.0f * (y * y + z * z);
        float R10 = 2.0f * (x * y + r * z);
        float R20 = 2.0f * (x * z - r * y);
        float R01 = 2.0f * (x * y - r * z);
        float R11 = 1.0f - 2.0f * (x * x + z * z);
        float R21 = 2.0f * (y * z + r * x);

        float u0 = s0 * R00, u1 = s0 * R10, u2 = s0 * R20;
        float v0 = s1 * R01, v1 = s1 * R11, v2 = s1 * R21;

        float p0 = p_k[3 * i + 0];
        float p1 = p_k[3 * i + 1];
        float p2 = p_k[3 * i + 2];

        float4 vm0 = vm[4 * i + 0];
        float4 vm1 = vm[4 * i + 1];
        float4 vm2 = vm[4 * i + 2];
        float4 vm3 = vm[4 * i + 3];

        float* o = &wlds[9 * l];        // banks (9l+j)%32: <=2 lanes/bank -> free
        o[0] = vm0.x * u0 + vm1.x * u1 + vm2.x * u2;
        o[1] = vm0.x * v0 + vm1.x * v1 + vm2.x * v2;
        o[2] = vm0.x * p0 + vm1.x * p1 + vm2.x * p2 + vm3.x;
        o[3] = vm0.y * u0 + vm1.y * u1 + vm2.y * u2;
        o[4] = vm0.y * v0 + vm1.y * v1 + vm2.y * v2;
        o[5] = vm0.y * p0 + vm1.y * p1 + vm2.y * p2 + vm3.y;
        o[6] = vm0.z * u0 + vm1.z * u1 + vm2.z * u2;
        o[7] = vm0.z * v0 + vm1.z * v1 + vm2.z * v2;
        o[8] = vm0.z * p0 + vm1.z * p1 + vm2.z * p2 + vm3.z;
    }

    // In-wave fence instead of __syncthreads(): lanes are lockstep within a
    // wave on CDNA; lgkmcnt(0) lands the ds_writes before cross-lane ds_reads.
    // sched_barrier stops the compiler hoisting the reads above it (rule 18).
    asm volatile("s_waitcnt lgkmcnt(0)" ::: "memory");
    __builtin_amdgcn_sched_barrier(0);

    const int g0 = base + w * 64;               // wave's first point
    if (g0 + 64 <= n) {
        // Full wave: 64 pts x 9 = 576 floats = 144 float4, contiguous.
        // Byte base (base + w*64)*36: base*36 = blk*9216 (16-al.), w*2304 (16-al.)
        const float4* lw4 = (const float4*)wlds;
        float4* gw4 = (float4*)(out + (size_t)g0 * 9);
        gw4[l]       = lw4[l];
        gw4[64 + l]  = lw4[64 + l];
        if (l < 16) gw4[128 + l] = lw4[128 + l];
    } else if (g0 < n) {
        // Ragged tail wave (unused for n=2e6, kept for correctness).
        const int cnt = (n - g0) * 9;
        for (int k = l; k < cnt; k += 64) out[(size_t)g0 * 9 + k] = wlds[k];
    }
}

extern "C" void kernel_launch(void* const* d_in, const int* in_sizes, int n_in,
                              void* d_out, int out_size, void* d_ws, size_t ws_size,
                              hipStream_t stream) {
    const float4* rot   = (const float4*)d_in[0];
    const float*  mod   = (const float*)d_in[1];
    const float2* scale = (const float2*)d_in[2];
    const float*  p_k   = (const float*)d_in[3];
    const float4* vm    = (const float4*)d_in[4];
    float* out = (float*)d_out;

    int n = in_sizes[0] / 4;  // rot has N*4 elements
    int block = 256;
    int grid = (n + PTS - 1) / PTS;
    cov_proj_kernel<<<grid, block, 0, stream>>>(rot, mod, scale, p_k, vm, out, n);
}